// Round 2
// baseline (5225.066 us; speedup 1.0000x reference)
//
#include <hip/hip_runtime.h>
#include <hip/hip_bf16.h>

#define D_MODEL 1024
#define NUM_HEADS 16
#define D_K 64
#define BATCH 2
#define SEQ 2048

typedef __attribute__((ext_vector_type(8))) short bf16x8;
typedef __attribute__((ext_vector_type(4))) float f32x4;

union P16 { int4 i4; ushort u[8]; };

__device__ __forceinline__ float bf2f(ushort u) {
    union { unsigned int i; float f; } c; c.i = ((unsigned int)u) << 16; return c.f;
}
__device__ __forceinline__ ushort f2bf(float f) {
    union { float f; unsigned int i; } c; c.f = f;
    unsigned int x = c.i;
    return (ushort)((x + 0x7fff + ((x >> 16) & 1)) >> 16);
}

// Decide whether float inputs are fp32 (flag=1) or bf16 (flag=0) from x's bits.
// Even ushort offsets: bf16 data -> valid N(0,1) exponents [114,129];
// fp32 data -> low mantissa halves, uniform exponent field (~16% plausible).
__global__ void detect_f32(const ushort* __restrict__ x, int* __restrict__ flag) {
    int lane = threadIdx.x;               // 64 threads
    ushort u = x[2 * lane];
    int e = (u >> 7) & 0xFF;
    bool plausible = (e >= 100 && e <= 141);
    unsigned long long b = __ballot(plausible);
    if (lane == 0) flag[0] = (__popcll(b) < 32) ? 1 : 0;
}

// Load 8 consecutive logical-bf16 elements starting at idx (idx % 8 == 0).
template<bool F32>
__device__ __forceinline__ int4 load8(const void* p, size_t idx) {
    if constexpr (F32) {
        const float* f = (const float*)p + idx;
        float4 a = *(const float4*)f;
        float4 b = *(const float4*)(f + 4);
        P16 r;
        r.u[0] = f2bf(a.x); r.u[1] = f2bf(a.y); r.u[2] = f2bf(a.z); r.u[3] = f2bf(a.w);
        r.u[4] = f2bf(b.x); r.u[5] = f2bf(b.y); r.u[6] = f2bf(b.z); r.u[7] = f2bf(b.w);
        return r.i4;
    } else {
        return *(const int4*)((const ushort*)p + idx);
    }
}
template<bool F32>
__device__ __forceinline__ float loadS(const void* p, int idx) {
    return F32 ? ((const float*)p)[idx] : bf2f(((const ushort*)p)[idx]);
}

// C[M][N] = A[M][K] @ W[K][N] + bias, fp32 accumulate.
// MODE 0: A internal bf16 ws; W/bias/out external (dtype per EXT). out[row*N+col].
// MODE 1: A/W/bias external; out internal bf16 ws, QKV scatter
//         -> out[(((which*B + b)*H + h)*S + s)*64 + dk]
template<int MODE, bool EXT>
__device__ __forceinline__ void gemm_body(ushort (*As)[40], ushort (*Bs)[40],
    const void* __restrict__ A, const void* __restrict__ W,
    const void* __restrict__ bias, void* __restrict__ out, int M, int N, int K)
{
    const int tid  = threadIdx.x;
    const int m0   = blockIdx.y * 64;
    const int n0   = blockIdx.x * 64;
    const int wave = tid >> 6, lane = tid & 63;
    const int wm   = (wave >> 1) * 32, wn = (wave & 1) * 32;
    const int ln   = lane & 15, quad = lane >> 4;

    f32x4 acc[2][2] = {};

    const int arow = tid >> 2, akq = (tid & 3) * 8;   // A stage: 64 m x 32 k
    const int bkk  = tid >> 3, bn0 = (tid & 7) * 8;   // W stage: 32 k x 64 n

    for (int k0 = 0; k0 < K; k0 += 32) {
        int4 av;
        if (MODE == 1) av = load8<EXT>(A, (size_t)(m0 + arow) * K + k0 + akq);
        else           av = load8<false>(A, (size_t)(m0 + arow) * K + k0 + akq);
        *(int4*)(&As[arow][akq]) = av;

        P16 bv;
        bv.i4 = load8<EXT>(W, (size_t)(k0 + bkk) * N + n0 + bn0);
        #pragma unroll
        for (int e = 0; e < 8; ++e) Bs[bn0 + e][bkk] = bv.u[e];

        __syncthreads();

        #pragma unroll
        for (int mi = 0; mi < 2; ++mi) {
            bf16x8 afrag = *(const bf16x8*)(&As[wm + mi * 16 + ln][quad * 8]);
            #pragma unroll
            for (int ni = 0; ni < 2; ++ni) {
                bf16x8 bfrag = *(const bf16x8*)(&Bs[wn + ni * 16 + ln][quad * 8]);
                acc[mi][ni] = __builtin_amdgcn_mfma_f32_16x16x32_bf16(
                    afrag, bfrag, acc[mi][ni], 0, 0, 0);
            }
        }
        __syncthreads();
    }

    #pragma unroll
    for (int mi = 0; mi < 2; ++mi) {
        #pragma unroll
        for (int ni = 0; ni < 2; ++ni) {
            int col = n0 + wn + ni * 16 + ln;
            float bb = loadS<EXT>(bias, col);
            #pragma unroll
            for (int r = 0; r < 4; ++r) {
                int row = m0 + wm + mi * 16 + quad * 4 + r;
                float v = acc[mi][ni][r] + bb;
                if (MODE == 0) {
                    if (EXT) ((float*)out)[(size_t)row * N + col] = v;
                    else     ((ushort*)out)[(size_t)row * N + col] = f2bf(v);
                } else {
                    int which = col >> 10;        // 0=Q 1=K 2=V
                    int h     = (col >> 6) & (NUM_HEADS - 1);
                    int dk    = col & (D_K - 1);
                    int b     = row >> 11;        // row / SEQ
                    int s     = row & (SEQ - 1);
                    ((ushort*)out)[((((size_t)which * BATCH + b) * NUM_HEADS + h) * SEQ + s) * D_K + dk] = f2bf(v);
                }
            }
        }
    }
}

template<int MODE>
__global__ __launch_bounds__(256)
void gemm_kernel(const void* __restrict__ A, const void* __restrict__ W,
                 const void* __restrict__ bias, void* __restrict__ out,
                 int M, int N, int K, const int* __restrict__ flag)
{
    __shared__ ushort As[64][40];   // pad 32->40 (80B rows, 16B aligned)
    __shared__ ushort Bs[64][40];
    if (*flag) gemm_body<MODE, true >(As, Bs, A, W, bias, out, M, N, K);
    else       gemm_body<MODE, false>(As, Bs, A, W, bias, out, M, N, K);
}

// One wave per query row, lane = dk. Online softmax over j<=i.
// Q/K/V in ws: [BH][S][64] bf16 (internal format, dtype-independent).
__global__ __launch_bounds__(256)
void attn_kernel(const ushort* __restrict__ Q, const ushort* __restrict__ Kt,
                 const ushort* __restrict__ V, ushort* __restrict__ attn)
{
    const int lane = threadIdx.x & 63;
    const int wave = threadIdx.x >> 6;
    const int r    = blockIdx.x * 4 + wave;       // 0 .. B*H*S-1
    const int bh   = r >> 11;
    int i          = r & (SEQ - 1);
    // pair short/long causal rows per block for load balance (bijection on [0,2048))
    i = (i & 1) ? (SEQ - 1 - (i >> 1)) : (i >> 1);

    const size_t base = (size_t)bh * SEQ * D_K;
    const float q = bf2f(Q[base + (size_t)i * D_K + lane]) * 0.125f; // 1/sqrt(64)

    float m = -1e30f, l = 0.f, o = 0.f;
    for (int j = 0; j <= i; ++j) {
        float kf = bf2f(Kt[base + (size_t)j * D_K + lane]);
        float s  = q * kf;
        #pragma unroll
        for (int off = 32; off >= 1; off >>= 1)
            s += __shfl_xor(s, off, 64);
        float nm    = fmaxf(m, s);
        float alpha = __expf(m - nm);
        float p     = __expf(s - nm);
        float vf    = bf2f(V[base + (size_t)j * D_K + lane]);
        l = l * alpha + p;
        o = o * alpha + p * vf;
        m = nm;
    }
    o /= l;

    const int b = bh >> 4, h = bh & (NUM_HEADS - 1);
    attn[(size_t)(b * SEQ + i) * D_MODEL + h * D_K + lane] = f2bf(o);
}

extern "C" void kernel_launch(void* const* d_in, const int* in_sizes, int n_in,
                              void* d_out, int out_size, void* d_ws, size_t ws_size,
                              hipStream_t stream)
{
    const void* x     = d_in[0];
    // d_in[1] = int32 tril mask -- causal handled analytically
    const void* w_qkv = d_in[2];
    const void* b_qkv = d_in[3];
    const void* w_out = d_in[4];
    const void* b_out = d_in[5];

    int*    flag    = (int*)d_ws;
    ushort* qkv_ws  = (ushort*)((char*)d_ws + 256);           // [3][B][H][S][64] bf16
    const size_t per = (size_t)BATCH * NUM_HEADS * SEQ * D_K; // 4.19M elems
    ushort* attn_ws = qkv_ws + 3 * per;                       // [B*S][1024] bf16

    const int M = BATCH * SEQ;  // 4096

    detect_f32<<<1, 64, 0, stream>>>((const ushort*)x, flag);

    dim3 g1(3 * D_MODEL / 64, M / 64);
    gemm_kernel<1><<<g1, 256, 0, stream>>>(x, w_qkv, b_qkv, qkv_ws,
                                           M, 3 * D_MODEL, D_MODEL, flag);

    attn_kernel<<<(BATCH * NUM_HEADS * SEQ) / 4, 256, 0, stream>>>(
        qkv_ws, qkv_ws + per, qkv_ws + 2 * per, attn_ws);

    dim3 g2(D_MODEL / 64, M / 64);
    gemm_kernel<0><<<g2, 256, 0, stream>>>(attn_ws, w_out, b_out, d_out,
                                           M, D_MODEL, D_MODEL, flag);
}

// Round 4
// 379.644 us; speedup vs baseline: 13.7631x; 13.7631x over previous
//
#include <hip/hip_runtime.h>
#include <hip/hip_bf16.h>

#define D_MODEL 1024
#define NUM_HEADS 16
#define D_K 64
#define BATCH 2
#define SEQ 2048

typedef __attribute__((ext_vector_type(8))) short bf16x8;
typedef __attribute__((ext_vector_type(4))) float f32x4;

union P16 { int4 i4; ushort u[8]; };

__device__ __forceinline__ float bf2f(ushort u) {
    union { unsigned int i; float f; } c; c.i = ((unsigned int)u) << 16; return c.f;
}
__device__ __forceinline__ ushort f2bf(float f) {
    union { float f; unsigned int i; } c; c.f = f;
    unsigned int x = c.i;
    return (ushort)((x + 0x7fff + ((x >> 16) & 1)) >> 16);
}

// Decide whether float inputs are fp32 (flag=1) or bf16 (flag=0) from x's bits.
__global__ void detect_f32(const ushort* __restrict__ x, int* __restrict__ flag) {
    int lane = threadIdx.x;               // 64 threads
    ushort u = x[2 * lane];
    int e = (u >> 7) & 0xFF;
    bool plausible = (e >= 100 && e <= 141);
    unsigned long long b = __ballot(plausible);
    if (lane == 0) flag[0] = (__popcll(b) < 32) ? 1 : 0;
}

template<bool F32>
__device__ __forceinline__ int4 load8(const void* p, size_t idx) {
    if constexpr (F32) {
        const float* f = (const float*)p + idx;
        float4 a = *(const float4*)f;
        float4 b = *(const float4*)(f + 4);
        P16 r;
        r.u[0] = f2bf(a.x); r.u[1] = f2bf(a.y); r.u[2] = f2bf(a.z); r.u[3] = f2bf(a.w);
        r.u[4] = f2bf(b.x); r.u[5] = f2bf(b.y); r.u[6] = f2bf(b.z); r.u[7] = f2bf(b.w);
        return r.i4;
    } else {
        return *(const int4*)((const ushort*)p + idx);
    }
}
template<bool F32>
__device__ __forceinline__ float loadS(const void* p, int idx) {
    return F32 ? ((const float*)p)[idx] : bf2f(((const ushort*)p)[idx]);
}

// ---------------- GEMM (unchanged, correctness-verified round 2) ----------------
// Tiles are 64 rows x 32 k -> [64][40] is correct HERE (k <= 31 < 40).
template<int MODE, bool EXT>
__device__ __forceinline__ void gemm_body(ushort (*As)[40], ushort (*Bs)[40],
    const void* __restrict__ A, const void* __restrict__ W,
    const void* __restrict__ bias, void* __restrict__ out, int M, int N, int K)
{
    const int tid  = threadIdx.x;
    const int m0   = blockIdx.y * 64;
    const int n0   = blockIdx.x * 64;
    const int wave = tid >> 6, lane = tid & 63;
    const int wm   = (wave >> 1) * 32, wn = (wave & 1) * 32;
    const int ln   = lane & 15, quad = lane >> 4;

    f32x4 acc[2][2] = {};

    const int arow = tid >> 2, akq = (tid & 3) * 8;
    const int bkk  = tid >> 3, bn0 = (tid & 7) * 8;

    for (int k0 = 0; k0 < K; k0 += 32) {
        int4 av;
        if (MODE == 1) av = load8<EXT>(A, (size_t)(m0 + arow) * K + k0 + akq);
        else           av = load8<false>(A, (size_t)(m0 + arow) * K + k0 + akq);
        *(int4*)(&As[arow][akq]) = av;

        P16 bv;
        bv.i4 = load8<EXT>(W, (size_t)(k0 + bkk) * N + n0 + bn0);
        #pragma unroll
        for (int e = 0; e < 8; ++e) Bs[bn0 + e][bkk] = bv.u[e];

        __syncthreads();

        #pragma unroll
        for (int mi = 0; mi < 2; ++mi) {
            bf16x8 afrag = *(const bf16x8*)(&As[wm + mi * 16 + ln][quad * 8]);
            #pragma unroll
            for (int ni = 0; ni < 2; ++ni) {
                bf16x8 bfrag = *(const bf16x8*)(&Bs[wn + ni * 16 + ln][quad * 8]);
                acc[mi][ni] = __builtin_amdgcn_mfma_f32_16x16x32_bf16(
                    afrag, bfrag, acc[mi][ni], 0, 0, 0);
            }
        }
        __syncthreads();
    }

    #pragma unroll
    for (int mi = 0; mi < 2; ++mi) {
        #pragma unroll
        for (int ni = 0; ni < 2; ++ni) {
            int col = n0 + wn + ni * 16 + ln;
            float bb = loadS<EXT>(bias, col);
            #pragma unroll
            for (int r = 0; r < 4; ++r) {
                int row = m0 + wm + mi * 16 + quad * 4 + r;
                float v = acc[mi][ni][r] + bb;
                if (MODE == 0) {
                    if (EXT) ((float*)out)[(size_t)row * N + col] = v;
                    else     ((ushort*)out)[(size_t)row * N + col] = f2bf(v);
                } else {
                    int which = col >> 10;
                    int h     = (col >> 6) & (NUM_HEADS - 1);
                    int dk    = col & (D_K - 1);
                    int b     = row >> 11;
                    int s     = row & (SEQ - 1);
                    ((ushort*)out)[((((size_t)which * BATCH + b) * NUM_HEADS + h) * SEQ + s) * D_K + dk] = f2bf(v);
                }
            }
        }
    }
}

template<int MODE>
__global__ __launch_bounds__(256)
void gemm_kernel(const void* __restrict__ A, const void* __restrict__ W,
                 const void* __restrict__ bias, void* __restrict__ out,
                 int M, int N, int K, const int* __restrict__ flag)
{
    __shared__ ushort As[64][40];
    __shared__ ushort Bs[64][40];
    if (*flag) gemm_body<MODE, true >(As, Bs, A, W, bias, out, M, N, K);
    else       gemm_body<MODE, false>(As, Bs, A, W, bias, out, M, N, K);
}

// ---------------- MFMA flash attention ----------------
// Block: one head (blockIdx.y = bh) x 64 q-rows. 4 waves x 16 q-rows each.
// Tiles here are 64 x 64 -> LDS width must be 64 + pad = 72.
// (Round-3 bug: width 40 aliased cols 40..63 onto the next row.)
// Row stride 144B = 9*16 -> b128 frag reads stay 16B-aligned; bank shift
// 4 dwords/row -> only 2-way lane aliasing on b128 reads (free per m136).
__global__ __launch_bounds__(256)
void flash_attn(const ushort* __restrict__ Q, const ushort* __restrict__ K,
                const ushort* __restrict__ V, ushort* __restrict__ attn)
{
    __shared__ ushort Qs[64][72];   // [qrow][dk]   (scaled by 1/8)
    __shared__ ushort Ks[64][72];   // [kvpos][dk]
    __shared__ ushort Vs[64][72];   // [dk][kvpos]  (transposed)
    __shared__ ushort Ps[64][72];   // [qrow][kvpos]

    const int tid  = threadIdx.x;
    const int wave = tid >> 6, lane = tid & 63;
    const int ln   = lane & 15, quad = lane >> 4;
    const int bh   = blockIdx.y;
    int qt = blockIdx.x;
    qt = (qt & 1) ? (31 - (qt >> 1)) : (qt >> 1);   // pair light+heavy q-tiles
    const int q0 = qt * 64;
    const size_t base = (size_t)bh * SEQ * D_K;

    // stage Q tile, pre-scaled by 1/sqrt(Dk)=0.125 (exact in bf16: exponent shift)
    {
        int r = tid >> 2, c = (tid & 3) * 16;
        #pragma unroll
        for (int hhh = 0; hhh < 2; ++hhh) {
            P16 v; v.i4 = *(const int4*)(Q + base + (size_t)(q0 + r) * D_K + c + hhh * 8);
            #pragma unroll
            for (int e = 0; e < 8; ++e) v.u[e] = f2bf(bf2f(v.u[e]) * 0.125f);
            *(int4*)(&Qs[r][c + hhh * 8]) = v.i4;
        }
    }
    __syncthreads();
    bf16x8 qfrag[2];
    qfrag[0] = *(const bf16x8*)(&Qs[wave * 16 + ln][quad * 8]);
    qfrag[1] = *(const bf16x8*)(&Qs[wave * 16 + ln][32 + quad * 8]);

    f32x4 acc_o[4] = {};
    float m_r[4], l_r[4];
    #pragma unroll
    for (int r = 0; r < 4; ++r) { m_r[r] = -1e30f; l_r[r] = 0.f; }

    const int ntiles = qt + 1;
    for (int jt = 0; jt < ntiles; ++jt) {
        const int j0 = jt * 64;
        __syncthreads();   // prior iteration's Ks/Vs reads complete

        // stage K tile [kv][dk]
        {
            int r = tid >> 2, c = (tid & 3) * 16;
            const ushort* src = K + base + (size_t)(j0 + r) * D_K + c;
            *(int4*)(&Ks[r][c])     = *(const int4*)(src);
            *(int4*)(&Ks[r][c + 8]) = *(const int4*)(src + 8);
        }
        // stage V transposed [dk][kv]: thread owns kv pair (2p,2p+1) x 8 dk,
        // packs two bf16 into one b32 LDS write
        {
            int p = tid & 31, dk0 = (tid >> 5) * 8;
            P16 v0, v1;
            v0.i4 = *(const int4*)(V + base + (size_t)(j0 + 2 * p)     * D_K + dk0);
            v1.i4 = *(const int4*)(V + base + (size_t)(j0 + 2 * p + 1) * D_K + dk0);
            #pragma unroll
            for (int e = 0; e < 8; ++e) {
                unsigned int pack = (unsigned int)v0.u[e] | ((unsigned int)v1.u[e] << 16);
                *(unsigned int*)(&Vs[dk0 + e][2 * p]) = pack;
            }
        }
        __syncthreads();

        // S = Q K^T : wave's 16 q-rows x 64 kv-cols (4 C-tiles)
        f32x4 s_acc[4];
        #pragma unroll
        for (int t = 0; t < 4; ++t) {
            bf16x8 k0 = *(const bf16x8*)(&Ks[t * 16 + ln][quad * 8]);
            bf16x8 k1 = *(const bf16x8*)(&Ks[t * 16 + ln][32 + quad * 8]);
            f32x4 z = {};
            z = __builtin_amdgcn_mfma_f32_16x16x32_bf16(qfrag[0], k0, z, 0, 0, 0);
            z = __builtin_amdgcn_mfma_f32_16x16x32_bf16(qfrag[1], k1, z, 0, 0, 0);
            s_acc[t] = z;
        }

        // causal mask on diagonal tile: col j0+t*16+ln vs row q0+wave*16+quad*4+r
        if (jt == ntiles - 1) {
            int rowb = q0 + wave * 16 + quad * 4;
            #pragma unroll
            for (int t = 0; t < 4; ++t)
                #pragma unroll
                for (int r = 0; r < 4; ++r)
                    if (j0 + t * 16 + ln > rowb + r) s_acc[t][r] = -1e30f;
        }

        // online softmax per row (row = quad*4 + r; 16-lane shuffle-reduce)
        float alpha[4];
        #pragma unroll
        for (int r = 0; r < 4; ++r) {
            float mx = fmaxf(fmaxf(s_acc[0][r], s_acc[1][r]),
                             fmaxf(s_acc[2][r], s_acc[3][r]));
            #pragma unroll
            for (int off = 8; off >= 1; off >>= 1)
                mx = fmaxf(mx, __shfl_xor(mx, off, 64));
            float mn = fmaxf(m_r[r], mx);
            alpha[r] = __expf(m_r[r] - mn);
            m_r[r] = mn;
            float sum = 0.f;
            #pragma unroll
            for (int t = 0; t < 4; ++t) {
                float pe = __expf(s_acc[t][r] - mn);
                Ps[wave * 16 + quad * 4 + r][t * 16 + ln] = f2bf(pe);
                sum += pe;
            }
            #pragma unroll
            for (int off = 8; off >= 1; off >>= 1)
                sum += __shfl_xor(sum, off, 64);
            l_r[r] = l_r[r] * alpha[r] + sum;
        }
        #pragma unroll
        for (int t = 0; t < 4; ++t)
            #pragma unroll
            for (int r = 0; r < 4; ++r)
                acc_o[t][r] *= alpha[r];

        // O += P @ V  (Ps rows [wave*16..+16) written by this same wave;
        // per-wave DS ops are in-order -> no barrier needed)
        #pragma unroll
        for (int s = 0; s < 2; ++s) {
            bf16x8 pf = *(const bf16x8*)(&Ps[wave * 16 + ln][s * 32 + quad * 8]);
            #pragma unroll
            for (int t = 0; t < 4; ++t) {
                bf16x8 vf = *(const bf16x8*)(&Vs[t * 16 + ln][s * 32 + quad * 8]);
                acc_o[t] = __builtin_amdgcn_mfma_f32_16x16x32_bf16(pf, vf, acc_o[t], 0, 0, 0);
            }
        }
    }

    // epilogue: normalize, write [B,S,H*64+dk]
    const int b = bh >> 4, hh = bh & (NUM_HEADS - 1);
    #pragma unroll
    for (int r = 0; r < 4; ++r) {
        float inv = 1.0f / l_r[r];
        int i = q0 + wave * 16 + quad * 4 + r;
        size_t rowoff = ((size_t)(b * SEQ + i)) * D_MODEL + hh * D_K;
        #pragma unroll
        for (int t = 0; t < 4; ++t)
            attn[rowoff + t * 16 + ln] = f2bf(acc_o[t][r] * inv);
    }
}

extern "C" void kernel_launch(void* const* d_in, const int* in_sizes, int n_in,
                              void* d_out, int out_size, void* d_ws, size_t ws_size,
                              hipStream_t stream)
{
    const void* x     = d_in[0];
    // d_in[1] = int32 tril mask -- causal handled analytically
    const void* w_qkv = d_in[2];
    const void* b_qkv = d_in[3];
    const void* w_out = d_in[4];
    const void* b_out = d_in[5];

    int*    flag    = (int*)d_ws;
    ushort* qkv_ws  = (ushort*)((char*)d_ws + 256);           // [3][B][H][S][64] bf16
    const size_t per = (size_t)BATCH * NUM_HEADS * SEQ * D_K;
    ushort* attn_ws = qkv_ws + 3 * per;                       // [B*S][1024] bf16

    const int M = BATCH * SEQ;  // 4096

    detect_f32<<<1, 64, 0, stream>>>((const ushort*)x, flag);

    dim3 g1(3 * D_MODEL / 64, M / 64);
    gemm_kernel<1><<<g1, 256, 0, stream>>>(x, w_qkv, b_qkv, qkv_ws,
                                           M, 3 * D_MODEL, D_MODEL, flag);

    dim3 ga(SEQ / 64, BATCH * NUM_HEADS);
    flash_attn<<<ga, 256, 0, stream>>>(qkv_ws, qkv_ws + per, qkv_ws + 2 * per, attn_ws);

    dim3 g2(D_MODEL / 64, M / 64);
    gemm_kernel<0><<<g2, 256, 0, stream>>>(attn_ws, w_out, b_out, d_out,
                                           M, D_MODEL, D_MODEL, flag);
}

// Round 5
// 290.862 us; speedup vs baseline: 17.9641x; 1.3052x over previous
//
#include <hip/hip_runtime.h>
#include <hip/hip_bf16.h>

#define D_MODEL 1024
#define NUM_HEADS 16
#define D_K 64
#define BATCH 2
#define SEQ 2048

typedef __attribute__((ext_vector_type(8))) short bf16x8;
typedef __attribute__((ext_vector_type(4))) float f32x4;

union P16 { int4 i4; ushort u[8]; };

__device__ __forceinline__ float bf2f(ushort u) {
    union { unsigned int i; float f; } c; c.i = ((unsigned int)u) << 16; return c.f;
}
__device__ __forceinline__ ushort f2bf(float f) {
    union { float f; unsigned int i; } c; c.f = f;
    unsigned int x = c.i;
    return (ushort)((x + 0x7fff + ((x >> 16) & 1)) >> 16);
}

// async 16B global->LDS (DMA; dest = wave-uniform base + lane*16)
typedef __attribute__((address_space(1))) void gv_t;
typedef __attribute__((address_space(3))) void lv_t;
__device__ __forceinline__ void gll16(const ushort* g, ushort* l) {
    __builtin_amdgcn_global_load_lds((gv_t*)g, (lv_t*)l, 16, 0, 0);
}

// Decide whether float inputs are fp32 (flag=1) or bf16 (flag=0) from x's bits.
__global__ void detect_f32(const ushort* __restrict__ x, int* __restrict__ flag) {
    int lane = threadIdx.x;               // 64 threads
    ushort u = x[2 * lane];
    int e = (u >> 7) & 0xFF;
    bool plausible = (e >= 100 && e <= 141);
    unsigned long long b = __ballot(plausible);
    if (lane == 0) flag[0] = (__popcll(b) < 32) ? 1 : 0;
}

// src (fp32 or bf16 per flag) -> dst bf16, 8 elems/thread
__global__ void convert_bf16(const void* __restrict__ src, ushort* __restrict__ dst,
                             int n, const int* __restrict__ flag) {
    int i = (blockIdx.x * 256 + threadIdx.x) * 8;
    if (i >= n) return;
    if (*flag) {
        const float* f = (const float*)src + i;
        float4 a = *(const float4*)f, b = *(const float4*)(f + 4);
        P16 r;
        r.u[0] = f2bf(a.x); r.u[1] = f2bf(a.y); r.u[2] = f2bf(a.z); r.u[3] = f2bf(a.w);
        r.u[4] = f2bf(b.x); r.u[5] = f2bf(b.y); r.u[6] = f2bf(b.z); r.u[7] = f2bf(b.w);
        *(int4*)(dst + i) = r.i4;
    } else {
        *(int4*)(dst + i) = *(const int4*)((const ushort*)src + i);
    }
}

// WT[n][k] = W[k][n], bf16 out. 64x64 tiles, 256 threads.
__global__ void transpose_w(const void* __restrict__ W, ushort* __restrict__ WT,
                            int K, int N, const int* __restrict__ flag) {
    __shared__ ushort t[64][72];
    const int tx = threadIdx.x;
    const int n0 = blockIdx.x * 64, k0 = blockIdx.y * 64;
    const bool f32 = (*flag) != 0;
    #pragma unroll
    for (int p = 0; p < 16; ++p) {
        int r = p * 4 + (tx >> 6), c = tx & 63;
        float v = f32 ? ((const float*)W)[(size_t)(k0 + r) * N + n0 + c]
                      : bf2f(((const ushort*)W)[(size_t)(k0 + r) * N + n0 + c]);
        t[r][c] = f2bf(v);
    }
    __syncthreads();
    #pragma unroll
    for (int p = 0; p < 16; ++p) {
        int nn = p * 4 + (tx >> 6), kk = tx & 63;
        WT[(size_t)(n0 + nn) * K + k0 + kk] = t[kk][nn];
    }
}

// ---------------- m97-style GEMM: 128x128 tile, BK=32, global_load_lds ----------------
// A[M][K] bf16, WT[N][K] bf16 (pre-transposed), bias bf16.
// LDS layout (both tiles): unpadded [128 rows][4 chunks of 16B]; global chunk
// (row, kc) stored at slot row*4 + (kc ^ ((row>>1)&3)). Frag reads undo the
// swizzle (phys = quad ^ ((ln>>1)&3)) -> every lane feeds logical k=quad*8+j
// (A/B consistent), banks spread to 2-way (free, m136).
// MODE 0: out[row*N+col] (dtype per flag). MODE 1: QKV scatter (bf16 ws).
template<int MODE>
__global__ __launch_bounds__(256)
void gemm128(const ushort* __restrict__ A, const ushort* __restrict__ WT,
             const ushort* __restrict__ bias, void* __restrict__ out,
             int N, int K, const int* __restrict__ flag)
{
    __shared__ ushort As[128 * 32];
    __shared__ ushort Bs[128 * 32];

    const int tid = threadIdx.x;
    const int w = tid >> 6, lane = tid & 63;
    const int ln = lane & 15, quad = lane >> 4;
    const int m0 = blockIdx.y * 128, n0 = blockIdx.x * 128;
    const int wm = (w >> 1) * 64, wn = (w & 1) * 64;

    // staging slots: s = w*128 + i*64 + lane (i=0,1); 512 chunks of 16B per tile
    const int s0 = w * 128 + lane, s1 = s0 + 64;
    const int ar0 = s0 >> 2, ak0 = ((s0 & 3) ^ ((ar0 >> 1) & 3)) * 8;
    const int ar1 = s1 >> 2, ak1 = ((s1 & 3) ^ ((ar1 >> 1) & 3)) * 8;
    const size_t aoff0 = (size_t)(m0 + ar0) * K + ak0;
    const size_t aoff1 = (size_t)(m0 + ar1) * K + ak1;
    const size_t boff0 = (size_t)(n0 + ar0) * K + ak0;
    const size_t boff1 = (size_t)(n0 + ar1) * K + ak1;
    ushort* asd0 = As + (size_t)(w * 2)     * 512;   // wave-uniform LDS bases
    ushort* asd1 = As + (size_t)(w * 2 + 1) * 512;
    ushort* bsd0 = Bs + (size_t)(w * 2)     * 512;
    ushort* bsd1 = Bs + (size_t)(w * 2 + 1) * 512;

    const int physc = (quad ^ ((ln >> 1) & 3)) * 8;  // un-swizzled frag chunk

    f32x4 acc[4][4] = {};

    for (int k0c = 0; k0c < K; k0c += 32) {
        __syncthreads();                 // prior iter's frag reads complete
        gll16(A  + aoff0 + k0c, asd0);
        gll16(A  + aoff1 + k0c, asd1);
        gll16(WT + boff0 + k0c, bsd0);
        gll16(WT + boff1 + k0c, bsd1);
        __syncthreads();                 // DMA drained (vmcnt(0) before barrier)

        bf16x8 af[4], bf[4];
        #pragma unroll
        for (int t = 0; t < 4; ++t) {
            af[t] = *(const bf16x8*)(As + (wm + t * 16 + ln) * 32 + physc);
            bf[t] = *(const bf16x8*)(Bs + (wn + t * 16 + ln) * 32 + physc);
        }
        #pragma unroll
        for (int mi = 0; mi < 4; ++mi)
            #pragma unroll
            for (int ni = 0; ni < 4; ++ni)
                acc[mi][ni] = __builtin_amdgcn_mfma_f32_16x16x32_bf16(
                    af[mi], bf[ni], acc[mi][ni], 0, 0, 0);
    }

    const int fmode = (MODE == 0) ? *flag : 0;
    #pragma unroll
    for (int mi = 0; mi < 4; ++mi) {
        #pragma unroll
        for (int ni = 0; ni < 4; ++ni) {
            int col = n0 + wn + ni * 16 + ln;
            float bb = bf2f(bias[col]);
            #pragma unroll
            for (int r = 0; r < 4; ++r) {
                int row = m0 + wm + mi * 16 + quad * 4 + r;
                float v = acc[mi][ni][r] + bb;
                if (MODE == 0) {
                    if (fmode) ((float*)out)[(size_t)row * N + col] = v;
                    else       ((ushort*)out)[(size_t)row * N + col] = f2bf(v);
                } else {
                    int which = col >> 10;
                    int h     = (col >> 6) & (NUM_HEADS - 1);
                    int dk    = col & (D_K - 1);
                    int b     = row >> 11;
                    int s     = row & (SEQ - 1);
                    ((ushort*)out)[((((size_t)which * BATCH + b) * NUM_HEADS + h) * SEQ + s) * D_K + dk] = f2bf(v);
                }
            }
        }
    }
}

// ---------------- MFMA flash attention (unchanged, verified round 4) ----------------
__global__ __launch_bounds__(256)
void flash_attn(const ushort* __restrict__ Q, const ushort* __restrict__ K,
                const ushort* __restrict__ V, ushort* __restrict__ attn)
{
    __shared__ ushort Qs[64][72];   // [qrow][dk]   (scaled by 1/8)
    __shared__ ushort Ks[64][72];   // [kvpos][dk]
    __shared__ ushort Vs[64][72];   // [dk][kvpos]  (transposed)
    __shared__ ushort Ps[64][72];   // [qrow][kvpos]

    const int tid  = threadIdx.x;
    const int wave = tid >> 6, lane = tid & 63;
    const int ln   = lane & 15, quad = lane >> 4;
    const int bh   = blockIdx.y;
    int qt = blockIdx.x;
    qt = (qt & 1) ? (31 - (qt >> 1)) : (qt >> 1);
    const int q0 = qt * 64;
    const size_t base = (size_t)bh * SEQ * D_K;

    {
        int r = tid >> 2, c = (tid & 3) * 16;
        #pragma unroll
        for (int hhh = 0; hhh < 2; ++hhh) {
            P16 v; v.i4 = *(const int4*)(Q + base + (size_t)(q0 + r) * D_K + c + hhh * 8);
            #pragma unroll
            for (int e = 0; e < 8; ++e) v.u[e] = f2bf(bf2f(v.u[e]) * 0.125f);
            *(int4*)(&Qs[r][c + hhh * 8]) = v.i4;
        }
    }
    __syncthreads();
    bf16x8 qfrag[2];
    qfrag[0] = *(const bf16x8*)(&Qs[wave * 16 + ln][quad * 8]);
    qfrag[1] = *(const bf16x8*)(&Qs[wave * 16 + ln][32 + quad * 8]);

    f32x4 acc_o[4] = {};
    float m_r[4], l_r[4];
    #pragma unroll
    for (int r = 0; r < 4; ++r) { m_r[r] = -1e30f; l_r[r] = 0.f; }

    const int ntiles = qt + 1;
    for (int jt = 0; jt < ntiles; ++jt) {
        const int j0 = jt * 64;
        __syncthreads();

        {
            int r = tid >> 2, c = (tid & 3) * 16;
            const ushort* src = K + base + (size_t)(j0 + r) * D_K + c;
            *(int4*)(&Ks[r][c])     = *(const int4*)(src);
            *(int4*)(&Ks[r][c + 8]) = *(const int4*)(src + 8);
        }
        {
            int p = tid & 31, dk0 = (tid >> 5) * 8;
            P16 v0, v1;
            v0.i4 = *(const int4*)(V + base + (size_t)(j0 + 2 * p)     * D_K + dk0);
            v1.i4 = *(const int4*)(V + base + (size_t)(j0 + 2 * p + 1) * D_K + dk0);
            #pragma unroll
            for (int e = 0; e < 8; ++e) {
                unsigned int pack = (unsigned int)v0.u[e] | ((unsigned int)v1.u[e] << 16);
                *(unsigned int*)(&Vs[dk0 + e][2 * p]) = pack;
            }
        }
        __syncthreads();

        f32x4 s_acc[4];
        #pragma unroll
        for (int t = 0; t < 4; ++t) {
            bf16x8 k0 = *(const bf16x8*)(&Ks[t * 16 + ln][quad * 8]);
            bf16x8 k1 = *(const bf16x8*)(&Ks[t * 16 + ln][32 + quad * 8]);
            f32x4 z = {};
            z = __builtin_amdgcn_mfma_f32_16x16x32_bf16(qfrag[0], k0, z, 0, 0, 0);
            z = __builtin_amdgcn_mfma_f32_16x16x32_bf16(qfrag[1], k1, z, 0, 0, 0);
            s_acc[t] = z;
        }

        if (jt == ntiles - 1) {
            int rowb = q0 + wave * 16 + quad * 4;
            #pragma unroll
            for (int t = 0; t < 4; ++t)
                #pragma unroll
                for (int r = 0; r < 4; ++r)
                    if (j0 + t * 16 + ln > rowb + r) s_acc[t][r] = -1e30f;
        }

        float alpha[4];
        #pragma unroll
        for (int r = 0; r < 4; ++r) {
            float mx = fmaxf(fmaxf(s_acc[0][r], s_acc[1][r]),
                             fmaxf(s_acc[2][r], s_acc[3][r]));
            #pragma unroll
            for (int off = 8; off >= 1; off >>= 1)
                mx = fmaxf(mx, __shfl_xor(mx, off, 64));
            float mn = fmaxf(m_r[r], mx);
            alpha[r] = __expf(m_r[r] - mn);
            m_r[r] = mn;
            float sum = 0.f;
            #pragma unroll
            for (int t = 0; t < 4; ++t) {
                float pe = __expf(s_acc[t][r] - mn);
                Ps[wave * 16 + quad * 4 + r][t * 16 + ln] = f2bf(pe);
                sum += pe;
            }
            #pragma unroll
            for (int off = 8; off >= 1; off >>= 1)
                sum += __shfl_xor(sum, off, 64);
            l_r[r] = l_r[r] * alpha[r] + sum;
        }
        #pragma unroll
        for (int t = 0; t < 4; ++t)
            #pragma unroll
            for (int r = 0; r < 4; ++r)
                acc_o[t][r] *= alpha[r];

        #pragma unroll
        for (int s = 0; s < 2; ++s) {
            bf16x8 pf = *(const bf16x8*)(&Ps[wave * 16 + ln][s * 32 + quad * 8]);
            #pragma unroll
            for (int t = 0; t < 4; ++t) {
                bf16x8 vf = *(const bf16x8*)(&Vs[t * 16 + ln][s * 32 + quad * 8]);
                acc_o[t] = __builtin_amdgcn_mfma_f32_16x16x32_bf16(pf, vf, acc_o[t], 0, 0, 0);
            }
        }
    }

    const int b = bh >> 4, hh = bh & (NUM_HEADS - 1);
    #pragma unroll
    for (int r = 0; r < 4; ++r) {
        float inv = 1.0f / l_r[r];
        int i = q0 + wave * 16 + quad * 4 + r;
        size_t rowoff = ((size_t)(b * SEQ + i)) * D_MODEL + hh * D_K;
        #pragma unroll
        for (int t = 0; t < 4; ++t)
            attn[rowoff + t * 16 + ln] = f2bf(acc_o[t][r] * inv);
    }
}

extern "C" void kernel_launch(void* const* d_in, const int* in_sizes, int n_in,
                              void* d_out, int out_size, void* d_ws, size_t ws_size,
                              hipStream_t stream)
{
    const void* x     = d_in[0];
    // d_in[1] = int32 tril mask -- causal handled analytically
    const void* w_qkv = d_in[2];
    const void* b_qkv = d_in[3];
    const void* w_out = d_in[4];
    const void* b_out = d_in[5];

    char* ws = (char*)d_ws;
    int*    flag   = (int*)ws;                  size_t off = 256;
    ushort* WqkvT  = (ushort*)(ws + off);       off += (size_t)3 * D_MODEL * D_MODEL * 2;
    ushort* WoutT  = (ushort*)(ws + off);       off += (size_t)D_MODEL * D_MODEL * 2;
    ushort* bq     = (ushort*)(ws + off);       off += 8192;
    ushort* bo     = (ushort*)(ws + off);       off += 8192;
    ushort* qkv_ws = (ushort*)(ws + off);       off += (size_t)3 * BATCH * NUM_HEADS * SEQ * D_K * 2;
    ushort* xb     = (ushort*)(ws + off);       // aliases attn_ws: xb dead after QKV gemm
    ushort* attn_ws = xb;

    const int M = BATCH * SEQ;          // 4096
    const size_t per = (size_t)BATCH * NUM_HEADS * SEQ * D_K;

    detect_f32<<<1, 64, 0, stream>>>((const ushort*)x, flag);

    const int nx = M * D_MODEL;         // 4.19M
    convert_bf16<<<nx / 8 / 256, 256, 0, stream>>>(x, xb, nx, flag);
    convert_bf16<<<2, 256, 0, stream>>>(b_qkv, bq, 3 * D_MODEL, flag);
    convert_bf16<<<1, 256, 0, stream>>>(b_out, bo, D_MODEL, flag);
    transpose_w<<<dim3(3 * D_MODEL / 64, D_MODEL / 64), 256, 0, stream>>>(
        w_qkv, WqkvT, D_MODEL, 3 * D_MODEL, flag);
    transpose_w<<<dim3(D_MODEL / 64, D_MODEL / 64), 256, 0, stream>>>(
        w_out, WoutT, D_MODEL, D_MODEL, flag);

    gemm128<1><<<dim3(3 * D_MODEL / 128, M / 128), 256, 0, stream>>>(
        xb, WqkvT, bq, qkv_ws, 3 * D_MODEL, D_MODEL, flag);

    dim3 ga(SEQ / 64, BATCH * NUM_HEADS);
    flash_attn<<<ga, 256, 0, stream>>>(qkv_ws, qkv_ws + per, qkv_ws + 2 * per, attn_ws);

    gemm128<0><<<dim3(D_MODEL / 128, M / 128), 256, 0, stream>>>(
        attn_ws, WoutT, bo, d_out, D_MODEL, D_MODEL, flag);
}